// Round 14
// baseline (308.166 us; speedup 1.0000x reference)
//
#include <hip/hip_runtime.h>
#include <hip/hip_bf16.h>
#include <hip/hip_fp16.h>
#include <math.h>

#define N_NODES 20000
#define FCH 64
#define ZSP 10
#define E_EDGES 320000
#define RDIM 8
#define EPSC 0.25f
#define SQRT3C 1.7320508075688772f
#define INV_SQRT3C 0.57735026918962576f
#define INV_F 0.125f  /* 1/sqrt(64) */

// ---- workspace layout (float offsets) ----
#define OFF_EUP    0                               // (N,64) uint2 fp16x4 = N*128 floats
#define OFF_SKS    (N_NODES*128)                   // (N,64)
#define OFF_SKV    (OFF_SKS + N_NODES*64)          // (N,3,64) planar
#define OFF_HSMID  (OFF_SKV + N_NODES*192)         // (N,64)
#define OFF_HVMID  (OFF_HSMID + N_NODES*64)        // (N,3,64) planar
#define OFF_WSCP   (OFF_HVMID + N_NODES*192)       // (Z,9,64)
#define OFF_FRAGS  (OFF_WSCP + ZSP*576)            // 3328*8 ushort = 13312 floats
#define OFF_WBUF   (OFF_FRAGS + 13312)             // E*64 uint2 (fp16x4 MESSAGES)
#define OFF_CSR    (OFF_WBUF + E_EDGES*128)        // erec float4[E], then ints
#define OFF_WF     (OFF_CSR + E_EDGES*4 + 360132)  // 416 slots * 512 ushort
// ints relative to csr int base (after erec):
#define CSR_CNT    0        /* 20000, becomes cursor after scan */
#define CSR_PTR    20000    /* 20001 */
#define CSR_SEID   40001    /* E */

// k_setup gid ranges
#define SU_WSC   5760                  /* 10*576 */
#define SU_PREP  (SU_WSC + 3328)
#define SU_PREP2 (SU_PREP + 26624)     /* 416*64 */
#define SU_HIST  (SU_PREP2 + E_EDGES)

typedef __attribute__((ext_vector_type(8))) short bhalf8;
typedef __attribute__((ext_vector_type(4))) float f32x4;

// fast silu: v_exp_f32 + v_rcp_f32 (err ~1ulp, negligible vs bf16 quantization)
__device__ __forceinline__ float silu_f(float x) {
    float e = __builtin_amdgcn_exp2f(x * -1.442695040888963f);
    return x * __builtin_amdgcn_rcpf(1.0f + e);
}

__device__ __forceinline__ unsigned short f2bf(float x) {
    unsigned int u = __float_as_uint(x);
    unsigned int r = u + 0x7FFFu + ((u >> 16) & 1u);   // RNE
    return (unsigned short)(r >> 16);
}

// packed pair -> one dword (lo in low 16); v_cvt_pk_bf16_f32 on gfx950
__device__ __forceinline__ unsigned int pack_bf2(float lo, float hi) {
    __hip_bfloat162 b = __float22bfloat162_rn(make_float2(lo, hi));
    return *(unsigned int*)&b;
}

// fp16 pair pack (lo in low 16)
__device__ __forceinline__ unsigned int pack_h2(float lo, float hi) {
    __half2 h = __floats2half2_rn(lo, hi);
    return *(unsigned int*)&h;
}

__device__ __forceinline__ bhalf8 mk8(unsigned a, unsigned b, unsigned c, unsigned d) {
    uint4 u; u.x = a; u.y = b; u.z = c; u.w = d;
    return *(bhalf8*)&u;
}

__device__ __forceinline__ float half_lo(unsigned v) {
    return __half2float(__ushort_as_half((unsigned short)(v & 0xFFFFu)));
}
__device__ __forceinline__ float half_hi(unsigned v) {
    return __half2float(__ushort_as_half((unsigned short)(v >> 16)));
}

// split fp32 -> bf16 hi (trunc) + bf16 lo (trunc of residual); err ~2^-16 rel
__device__ __forceinline__ void split_f32(float x, short& h, short& l) {
    unsigned int u = __float_as_uint(x);
    unsigned int hb = u & 0xFFFF0000u;
    h = (short)(u >> 16);
    float r = x - __uint_as_float(hb);
    l = (short)(__float_as_uint(r) >> 16);
}

__device__ __forceinline__ int species_of(int n, const int* counts) {
    int acc = 0, s = ZSP - 1;
#pragma unroll
    for (int z = 0; z < ZSP; z++) {
        int c = counts[z];
        if (n >= acc && n < acc + c) s = z;
        acc += c;
    }
    return s;
}

// K-setup: fused wscproj + prep(MLP frags) + prep2(node frags) + hist.
__global__ __launch_bounds__(256) void k_setup(
    const float* __restrict__ Wsc, const float* __restrict__ Proj, float* __restrict__ wscp,
    const float* __restrict__ R1, const float* __restrict__ R2,
    const float* __restrict__ R3, const float* __restrict__ R4,
    unsigned short* __restrict__ frags,
    const float* __restrict__ Wup0, const float* __restrict__ Wup1,
    const float* __restrict__ Ws0, const float* __restrict__ Ws1,
    const float* __restrict__ Wd0, const float* __restrict__ Wd1,
    const float* __restrict__ Wl0, const float* __restrict__ Wl1,
    unsigned short* __restrict__ wf,
    const int* __restrict__ receivers, int* __restrict__ csr) {
    int gid = blockIdx.x * 256 + threadIdx.x;
    if (gid < SU_WSC) {
        int z = gid / 576, t = gid % 576;
        int b = t >> 6, u = t & 63;
        float acc = 0.f;
#pragma unroll
        for (int p = 0; p < 9; p++) acc += Wsc[z * 576 + p * 64 + u] * Proj[p * 9 + b];
        wscp[z * 576 + b * 64 + u] = acc;
    } else if (gid < SU_PREP) {
        int id = gid - SU_WSC;
        int lane = id & 63, fi = id >> 6;
        int quad = lane >> 4, l15 = lane & 15;
        const float* W;
        int s, t, N;
        bool r1 = false;
        if (fi < 4)       { W = R1; s = 0; t = fi; N = 64; r1 = true; }
        else if (fi < 12) { W = R2; int x = fi - 4;  s = x >> 2; t = x & 3;  N = 64; }
        else if (fi < 20) { W = R3; int x = fi - 12; s = x >> 2; t = x & 3;  N = 64; }
        else              { W = R4; int x = fi - 20; s = x >> 4; t = x & 15; N = 256; }
        unsigned int v[4];
#pragma unroll
        for (int jj = 0; jj < 4; jj++) {
            unsigned short pk2[2];
#pragma unroll
            for (int o = 0; o < 2; o++) {
                int j = jj * 2 + o;
                int k = s * 32 + quad * 8 + j, n = t * 16 + l15;
                float val = (r1 && k >= RDIM) ? 0.f : W[k * N + n];
                pk2[o] = f2bf(val);
            }
            v[jj] = (unsigned int)pk2[0] | ((unsigned int)pk2[1] << 16);
        }
        uint4 pk; pk.x = v[0]; pk.y = v[1]; pk.z = v[2]; pk.w = v[3];
        ((uint4*)frags)[id] = pk;
    } else if (gid < SU_PREP2) {
        int id = gid - SU_PREP;
        int lane = id & 63, slot = id >> 6;
        int t = slot & 3, s = (slot >> 2) & 1, part = (slot >> 3) & 1, mat = slot >> 4;
        int quad = lane >> 4, l15 = lane & 15;
        const float* W;
        if (mat == 0)       W = Wup0;
        else if (mat == 1)  W = Wup1;
        else if (mat < 12)  W = Ws0 + (mat - 2) * 4096;
        else if (mat < 22)  W = Ws1 + (mat - 12) * 4096;
        else if (mat == 22) W = Wd0;
        else if (mat == 23) W = Wd1;
        else if (mat == 24) W = Wl0;
        else                W = Wl1;
        unsigned int v[4];
#pragma unroll
        for (int jj = 0; jj < 4; jj++) {
            unsigned short pk2[2];
#pragma unroll
            for (int o = 0; o < 2; o++) {
                int j = jj * 2 + o;
                int k = s * 32 + quad * 8 + j, n = t * 16 + l15;
                float x = W[k * 64 + n];
                short h, l;
                split_f32(x, h, l);
                pk2[o] = part == 0 ? (unsigned short)h : (unsigned short)l;
            }
            v[jj] = (unsigned int)pk2[0] | ((unsigned int)pk2[1] << 16);
        }
        uint4 pk; pk.x = v[0]; pk.y = v[1]; pk.z = v[2]; pk.w = v[3];
        ((uint4*)wf)[id] = pk;
    } else if (gid < SU_HIST) {
        int e = gid - SU_PREP2;
        atomicAdd(&csr[CSR_CNT + receivers[e]], 1);
    }
}

// Single-dispatch scan: one block, 1024 threads, shuffle-based.
__global__ __launch_bounds__(1024) void k_scan_all(int* __restrict__ csr) {
    __shared__ int wsum[16];
    __shared__ int carry;
    int t = threadIdx.x, lane = t & 63, wv = t >> 6;
    int running = 0;
    for (int i0 = 0; i0 < N_NODES; i0 += 1024) {
        int i = i0 + t;
        int x = (i < N_NODES) ? csr[CSR_CNT + i] : 0;
        int s = x;
#pragma unroll
        for (int off = 1; off < 64; off <<= 1) {
            int v = __shfl_up(s, off, 64);
            if (lane >= off) s += v;
        }
        if (lane == 63) wsum[wv] = s;
        __syncthreads();
        if (wv == 0 && lane < 16) {
            int v = wsum[lane];
            int sc = v;
#pragma unroll
            for (int off = 1; off < 16; off <<= 1) {
                int u = __shfl_up(sc, off, 64);
                if (lane >= off) sc += u;
            }
            wsum[lane] = sc - v;       // exclusive wave offset
            if (lane == 15) carry = sc; // iteration total
        }
        __syncthreads();
        int excl = s - x + wsum[wv];
        if (i < N_NODES) {
            int val = running + excl;
            csr[CSR_PTR + i] = val;
            csr[CSR_CNT + i] = val;     // cursor for bucketing
        }
        running += carry;
        __syncthreads();               // protect wsum/carry before next iter
    }
    if (t == 0) csr[CSR_PTR + N_NODES] = running;
}

// Merged: blocks 0..1249 = node_pre (linear_up fp16-packed + species skip),
//         blocks 1250..2499 = bucket (CSR fill + Y1/sender precompute).
__global__ __launch_bounds__(256) void k_pre_bucket(
    const float* __restrict__ ns, const float* __restrict__ nv,
    const int* __restrict__ counts, const unsigned short* __restrict__ wf,
    const float* __restrict__ vectors, const int* __restrict__ senders,
    const int* __restrict__ receivers, int* __restrict__ csr,
    float4* __restrict__ erec, float* __restrict__ ws) {
    __shared__ uint2 eup_t[16][64];   // 8 KB (node_pre blocks only)
    int tid = threadIdx.x;
    if (blockIdx.x >= 1250) {
        // ---- bucket ----
        int e = (blockIdx.x - 1250) * 256 + tid;   // 1250*256 == E exactly
        int pos = atomicAdd(&csr[CSR_CNT + receivers[e]], 1);
        float v0 = vectors[e * 3 + 0], v1 = vectors[e * 3 + 1], v2 = vectors[e * 3 + 2];
        float s = SQRT3C * rsqrtf(v0 * v0 + v1 * v1 + v2 * v2);
        csr[CSR_SEID + pos] = e;
        float4 r;
        r.x = v0 * s; r.y = v1 * s; r.z = v2 * s; r.w = __int_as_float(senders[e]);
        erec[pos] = r;
        return;
    }
    // ---- node_pre ----
    int w = tid >> 6, lane = tid & 63;
    int q = lane >> 4, l15 = lane & 15;
    int nw = blockIdx.x * 16;
    int sid = species_of(nw, counts);
    const f32x4 z4 = {0.f, 0.f, 0.f, 0.f};

    bhalf8 Ah[2], Al[2];
    if (w == 0) {
#pragma unroll
        for (int s = 0; s < 2; s++) {
            const float* rp = ns + (size_t)(nw + l15) * 64 + s * 32 + q * 8;
            float4 a = *(const float4*)rp, b = *(const float4*)(rp + 4);
            float x[8] = {a.x, a.y, a.z, a.w, b.x, b.y, b.z, b.w};
#pragma unroll
            for (int j = 0; j < 8; j++) { short h, l; split_f32(x[j], h, l); Ah[s][j] = h; Al[s][j] = l; }
        }
    } else {
        int i = w - 1;
#pragma unroll
        for (int s = 0; s < 2; s++) {
            const float* rp = nv + (size_t)(nw + l15) * 192 + i;
#pragma unroll
            for (int j = 0; j < 8; j++) {
                float x = rp[(s * 32 + q * 8 + j) * 3];
                short h, l; split_f32(x, h, l); Ah[s][j] = h; Al[s][j] = l;
            }
        }
    }

    const bhalf8* wfv = (const bhalf8*)wf;
    float* sks = ws + OFF_SKS;
    float* skv = ws + OFF_SKV;

    // m=0: linear_up -> fp16 packed LDS tile
    {
        int mat = (w == 0) ? 0 : 1;
#pragma unroll
        for (int t = 0; t < 4; t++) {
            f32x4 acc = z4;
#pragma unroll
            for (int s = 0; s < 2; s++) {
                bhalf8 bh = wfv[(size_t)(mat * 16 + 0 + s * 4 + t) * 64 + lane];
                bhalf8 bl = wfv[(size_t)(mat * 16 + 8 + s * 4 + t) * 64 + lane];
                acc = __builtin_amdgcn_mfma_f32_16x16x32_bf16(Ah[s], bh, acc, 0, 0, 0);
                acc = __builtin_amdgcn_mfma_f32_16x16x32_bf16(Al[s], bh, acc, 0, 0, 0);
                acc = __builtin_amdgcn_mfma_f32_16x16x32_bf16(Ah[s], bl, acc, 0, 0, 0);
            }
#pragma unroll
            for (int r = 0; r < 4; r++) {
                unsigned short us = __half_as_ushort(__float2half_rn(acc[r] * INV_F));
                ((unsigned short*)&eup_t[q * 4 + r][t * 16 + l15])[w] = us;
            }
        }
    }
    // m=1: species skip -> fp32 tables
    {
        int mat = (w == 0) ? 2 + sid : 12 + sid;
        float* dst = (w == 0) ? sks : skv;
        int stride = (w == 0) ? 64 : 192;
        int off = (w == 0) ? 0 : (w - 1) * 64;
#pragma unroll
        for (int t = 0; t < 4; t++) {
            f32x4 acc = z4;
#pragma unroll
            for (int s = 0; s < 2; s++) {
                bhalf8 bh = wfv[(size_t)(mat * 16 + 0 + s * 4 + t) * 64 + lane];
                bhalf8 bl = wfv[(size_t)(mat * 16 + 8 + s * 4 + t) * 64 + lane];
                acc = __builtin_amdgcn_mfma_f32_16x16x32_bf16(Ah[s], bh, acc, 0, 0, 0);
                acc = __builtin_amdgcn_mfma_f32_16x16x32_bf16(Al[s], bh, acc, 0, 0, 0);
                acc = __builtin_amdgcn_mfma_f32_16x16x32_bf16(Ah[s], bl, acc, 0, 0, 0);
            }
#pragma unroll
            for (int r = 0; r < 4; r++)
                dst[(size_t)(nw + q * 4 + r) * stride + off + t * 16 + l15] = acc[r] * INV_F;
        }
    }
    __syncthreads();
    uint2* eup = (uint2*)(ws + OFF_EUP);
    for (int k = tid; k < 1024; k += 256) {
        int n = k >> 6, f = k & 63;
        eup[(size_t)(nw + n) * 64 + f] = eup_t[n][f];
    }
}

// Cross-lane frag builder (see R9 derivation).
template<int S>
__device__ __forceinline__ bhalf8 xfrag(const unsigned* pkA, const unsigned* pkB,
                                        int q, int l15) {
    int L0 = ((q & 1) << 5) + l15;
    int L1 = L0 + 16;
    bool hi = (q >> 1) != 0;
    unsigned a0 = (unsigned)__shfl((int)pkA[2 * S], L0, 64);
    unsigned a1 = (unsigned)__shfl((int)pkA[2 * S + 1], L0, 64);
    unsigned b0 = (unsigned)__shfl((int)pkB[2 * S], L0, 64);
    unsigned b1 = (unsigned)__shfl((int)pkB[2 * S + 1], L0, 64);
    unsigned c0 = (unsigned)__shfl((int)pkA[2 * S], L1, 64);
    unsigned c1 = (unsigned)__shfl((int)pkA[2 * S + 1], L1, 64);
    unsigned e0 = (unsigned)__shfl((int)pkB[2 * S], L1, 64);
    unsigned e1 = (unsigned)__shfl((int)pkB[2 * S + 1], L1, 64);
    return mk8(hi ? a1 : a0, hi ? b1 : b0, hi ? c1 : c0, hi ? e1 : e0);
}

// K2a: radial MLP via bf16 MFMA + full message computation.
// NO LDS at all: R4 fragments are read straight from global (52 KB table,
// L2-broadcast-resident — the compiler was already re-loading "register"
// frags from L2 per use at VGPR=64, so LDS staging only cost occupancy).
__global__ __launch_bounds__(256) void k_mlp(
    const float* __restrict__ radial, const unsigned short* __restrict__ frags,
    const int* __restrict__ csr, const float4* __restrict__ erec,
    unsigned short* __restrict__ wbuf, const float* __restrict__ ws) {
    int tid = threadIdx.x;
    int lane = tid & 63, w = tid >> 6, quad = lane >> 4, l15 = lane & 15;

    const bhalf8* fr = (const bhalf8*)frags;
    bhalf8 r1f[4], r2f[2][4], r3f[2][4];
#pragma unroll
    for (int t = 0; t < 4; t++) r1f[t] = fr[t * 64 + lane];
#pragma unroll
    for (int s = 0; s < 2; s++)
#pragma unroll
        for (int t = 0; t < 4; t++) {
            r2f[s][t] = fr[(4 + s * 4 + t) * 64 + lane];
            r3f[s][t] = fr[(12 + s * 4 + t) * 64 + lane];
        }

    const f32x4 z4 = {0.f, 0.f, 0.f, 0.f};
    const bhalf8* r4f = fr + 20 * 64;    // global, L2-resident
    const uint2* eup = (const uint2*)(ws + OFF_EUP);

    int el0 = (blockIdx.x * 4 + w) * 16;   // global sorted slot base

    bhalf8 af = {0, 0, 0, 0, 0, 0, 0, 0};
    if (quad == 0) {
        int eid = csr[CSR_SEID + el0 + l15];  // global edge id
        const float* rp = radial + (size_t)eid * 8;
        float4 ra = *(const float4*)rp;
        float4 rb = *(const float4*)(rp + 4);
        af[0] = (short)f2bf(ra.x); af[1] = (short)f2bf(ra.y);
        af[2] = (short)f2bf(ra.z); af[3] = (short)f2bf(ra.w);
        af[4] = (short)f2bf(rb.x); af[5] = (short)f2bf(rb.y);
        af[6] = (short)f2bf(rb.z); af[7] = (short)f2bf(rb.w);
    }
    unsigned pkA[4], pkB[4];
    {
        f32x4 acc[4];
#pragma unroll
        for (int t = 0; t < 4; t++)
            acc[t] = __builtin_amdgcn_mfma_f32_16x16x32_bf16(r1f[t], af, z4, 0, 0, 0);
#pragma unroll
        for (int t = 0; t < 4; t++) {
            pkA[t] = pack_bf2(silu_f(acc[t][0]), silu_f(acc[t][1]));
            pkB[t] = pack_bf2(silu_f(acc[t][2]), silu_f(acc[t][3]));
        }
    }
#pragma unroll
    for (int layer = 0; layer < 2; layer++) {
        bhalf8 b0 = xfrag<0>(pkA, pkB, quad, l15);
        bhalf8 b1 = xfrag<1>(pkA, pkB, quad, l15);
        f32x4 acc[4];
#pragma unroll
        for (int t = 0; t < 4; t++) {
            bhalf8 w0 = layer == 0 ? r2f[0][t] : r3f[0][t];
            bhalf8 w1 = layer == 0 ? r2f[1][t] : r3f[1][t];
            acc[t] = __builtin_amdgcn_mfma_f32_16x16x32_bf16(
                w1, b1, __builtin_amdgcn_mfma_f32_16x16x32_bf16(w0, b0, z4, 0, 0, 0), 0, 0, 0);
        }
#pragma unroll
        for (int t = 0; t < 4; t++) {
            pkA[t] = pack_bf2(silu_f(acc[t][0]), silu_f(acc[t][1]));
            pkB[t] = pack_bf2(silu_f(acc[t][2]), silu_f(acc[t][3]));
        }
    }
    {
        bhalf8 a0 = xfrag<0>(pkA, pkB, quad, l15);
        bhalf8 a1 = xfrag<1>(pkA, pkB, quad, l15);
        // per-r edge records (same across the 16 l15 lanes -> broadcast loads)
        float4 rc[4];
        int sx[4];
#pragma unroll
        for (int r = 0; r < 4; r++) {
            rc[r] = erec[el0 + quad * 4 + r];
            sx[r] = __float_as_int(rc[r].w);
        }
#pragma unroll
        for (int t4 = 0; t4 < 4; t4++) {
            int f = t4 * 16 + l15;
            // issue gathers first; MFMA chains below cover their latency
            uint2 ev[4];
#pragma unroll
            for (int r = 0; r < 4; r++)
                ev[r] = eup[(size_t)sx[r] * 64 + f];
            f32x4 p0 = __builtin_amdgcn_mfma_f32_16x16x32_bf16(
                a1, r4f[(16 + t4) * 64 + lane],
                __builtin_amdgcn_mfma_f32_16x16x32_bf16(a0, r4f[t4 * 64 + lane], z4, 0, 0, 0), 0, 0, 0);
            f32x4 p1 = __builtin_amdgcn_mfma_f32_16x16x32_bf16(
                a1, r4f[(20 + t4) * 64 + lane],
                __builtin_amdgcn_mfma_f32_16x16x32_bf16(a0, r4f[(4 + t4) * 64 + lane], z4, 0, 0, 0), 0, 0, 0);
            f32x4 p2 = __builtin_amdgcn_mfma_f32_16x16x32_bf16(
                a1, r4f[(24 + t4) * 64 + lane],
                __builtin_amdgcn_mfma_f32_16x16x32_bf16(a0, r4f[(8 + t4) * 64 + lane], z4, 0, 0, 0), 0, 0, 0);
            f32x4 p3 = __builtin_amdgcn_mfma_f32_16x16x32_bf16(
                a1, r4f[(28 + t4) * 64 + lane],
                __builtin_amdgcn_mfma_f32_16x16x32_bf16(a0, r4f[(12 + t4) * 64 + lane], z4, 0, 0, 0), 0, 0, 0);
#pragma unroll
            for (int r = 0; r < 4; r++) {
                float es = half_lo(ev[r].x), e0 = half_hi(ev[r].x);
                float e1 = half_lo(ev[r].y), e2 = half_hi(ev[r].y);
                float dot = e0 * rc[r].x + e1 * rc[r].y + e2 * rc[r].z;
                float ms = p0[r] * es + p1[r] * dot * INV_SQRT3C;
                float t3 = p3[r] * es * INV_SQRT3C;
                float m0 = p2[r] * e0 + t3 * rc[r].x;
                float m1 = p2[r] * e1 + t3 * rc[r].y;
                float m2 = p2[r] * e2 + t3 * rc[r].z;
                int el = el0 + quad * 4 + r;
                uint2 pk;
                pk.x = pack_h2(ms, m0);
                pk.y = pack_h2(m1, m2);
                ((uint2*)wbuf)[(size_t)el * 64 + f] = pk;
            }
        }
    }
}

// K2b: pure-stream message reduction per node. No random reads at all.
__global__ __launch_bounds__(256) void k_tp_gather(
    const unsigned short* __restrict__ wbuf, const int* __restrict__ csr,
    float* __restrict__ ws) {
    int tid = threadIdx.x, w = tid >> 6, f = tid & 63;
    int n = blockIdx.x * 4 + w;
    float* hs_mid = ws + OFF_HSMID;
    float* hv_mid = ws + OFF_HVMID;
    int beg = csr[CSR_PTR + n], end = csr[CSR_PTR + n + 1];
    float ams = 0.f, am0 = 0.f, am1 = 0.f, am2 = 0.f;
    if (beg < end) {
        int last = end - 1;
        uint2 mA = ((const uint2*)wbuf)[(size_t)beg * 64 + f];
        for (int i = beg; i < end; i++) {
            int j1 = (i + 1 < end) ? i + 1 : last;
            uint2 mB = ((const uint2*)wbuf)[(size_t)j1 * 64 + f];
            ams += half_lo(mA.x); am0 += half_hi(mA.x);
            am1 += half_lo(mA.y); am2 += half_hi(mA.y);
            mA = mB;
        }
    }
    hs_mid[n * 64 + f] = ams * EPSC;
    hv_mid[n * 192 + f] = am0 * EPSC;
    hv_mid[n * 192 + 64 + f] = am1 * EPSC;
    hv_mid[n * 192 + 128 + f] = am2 * EPSC;
}

// K3: linear_down + contraction + linear_sc + skip + readout via split-bf16 MFMA.
__global__ __launch_bounds__(256) void k_node_post(
    const int* __restrict__ counts, const unsigned short* __restrict__ wf,
    const float* __restrict__ Wr, float* __restrict__ ws, float* __restrict__ out) {
    __shared__ float T[4][16][68];
    int tid = threadIdx.x, w = tid >> 6, lane = tid & 63;
    int q = lane >> 4, l15 = lane & 15;
    int nw = blockIdx.x * 16;
    int sid = species_of(nw, counts);
    const f32x4 z4 = {0.f, 0.f, 0.f, 0.f};
    const bhalf8* wfv = (const bhalf8*)wf;
    const float* hs_mid = ws + OFF_HSMID;
    const float* hv_mid = ws + OFF_HVMID;
    const float* sks = ws + OFF_SKS;
    const float* skv = ws + OFF_SKV;
    const float* wscp = ws + OFF_WSCP;

    // Phase 1: linear_down (EPS already applied in k_tp_gather's store)
    {
        const float* src = (w == 0) ? hs_mid + (size_t)nw * 64
                                    : hv_mid + (size_t)nw * 192 + (w - 1) * 64;
        int rstride = (w == 0) ? 64 : 192;
        bhalf8 Ah[2], Al[2];
#pragma unroll
        for (int s = 0; s < 2; s++) {
            const float* rp = src + (size_t)l15 * rstride + s * 32 + q * 8;
            float4 a = *(const float4*)rp, b = *(const float4*)(rp + 4);
            float x[8] = {a.x, a.y, a.z, a.w, b.x, b.y, b.z, b.w};
#pragma unroll
            for (int j = 0; j < 8; j++) { short h, l; split_f32(x[j], h, l); Ah[s][j] = h; Al[s][j] = l; }
        }
        int mat = (w == 0) ? 22 : 23;
#pragma unroll
        for (int t = 0; t < 4; t++) {
            f32x4 acc = z4;
#pragma unroll
            for (int s = 0; s < 2; s++) {
                bhalf8 bh = wfv[(size_t)(mat * 16 + 0 + s * 4 + t) * 64 + lane];
                bhalf8 bl = wfv[(size_t)(mat * 16 + 8 + s * 4 + t) * 64 + lane];
                acc = __builtin_amdgcn_mfma_f32_16x16x32_bf16(Ah[s], bh, acc, 0, 0, 0);
                acc = __builtin_amdgcn_mfma_f32_16x16x32_bf16(Al[s], bh, acc, 0, 0, 0);
                acc = __builtin_amdgcn_mfma_f32_16x16x32_bf16(Ah[s], bl, acc, 0, 0, 0);
            }
#pragma unroll
            for (int r = 0; r < 4; r++)
                T[w][q * 4 + r][t * 16 + l15] = acc[r] * INV_F;
        }
    }
    __syncthreads();

    // Phase 2: symmetric contraction
    {
        int col = tid & 63, rg = tid >> 6;
        float wv[9];
#pragma unroll
        for (int b = 0; b < 9; b++) wv[b] = wscp[sid * 576 + b * 64 + col];
#pragma unroll
        for (int rr = 0; rr < 4; rr++) {
            int row = rg * 4 + rr;
            float hs = T[0][row][col];
            float h0 = T[1][row][col], h1 = T[2][row][col], h2 = T[3][row][col];
            float vv = h0 * h0 + h1 * h1 + h2 * h2;
            float cs = wv[0] * hs + wv[1] * hs * hs + wv[2] * vv
                     + wv[3] * hs * hs * hs + wv[4] * hs * vv;
            float fv = wv[5] + wv[6] * hs + wv[7] * hs * hs + wv[8] * vv;
            T[0][row][col] = cs;
            T[1][row][col] = h0 * fv;
            T[2][row][col] = h1 * fv;
            T[3][row][col] = h2 * fv;
        }
    }
    __syncthreads();

    // Phase 3: linear_sc + skip + store (+ readout on w0)
    {
        bhalf8 Ah[2], Al[2];
#pragma unroll
        for (int s = 0; s < 2; s++) {
            const float* rp = &T[w][l15][s * 32 + q * 8];
            float4 a = *(const float4*)rp, b = *(const float4*)(rp + 4);
            float x[8] = {a.x, a.y, a.z, a.w, b.x, b.y, b.z, b.w};
#pragma unroll
            for (int j = 0; j < 8; j++) { short h, l; split_f32(x[j], h, l); Ah[s][j] = h; Al[s][j] = l; }
        }
        int mat = (w == 0) ? 24 : 25;
        float* d_hs = out + N_NODES;
        float* d_hv = out + N_NODES + N_NODES * 64;
        float p[4] = {0.f, 0.f, 0.f, 0.f};
#pragma unroll
        for (int t = 0; t < 4; t++) {
            f32x4 acc = z4;
#pragma unroll
            for (int s = 0; s < 2; s++) {
                bhalf8 bh = wfv[(size_t)(mat * 16 + 0 + s * 4 + t) * 64 + lane];
                bhalf8 bl = wfv[(size_t)(mat * 16 + 8 + s * 4 + t) * 64 + lane];
                acc = __builtin_amdgcn_mfma_f32_16x16x32_bf16(Ah[s], bh, acc, 0, 0, 0);
                acc = __builtin_amdgcn_mfma_f32_16x16x32_bf16(Al[s], bh, acc, 0, 0, 0);
                acc = __builtin_amdgcn_mfma_f32_16x16x32_bf16(Ah[s], bl, acc, 0, 0, 0);
            }
            int col = t * 16 + l15;
            if (w == 0) {
                float wr = Wr[col];
#pragma unroll
                for (int r = 0; r < 4; r++) {
                    int gn = nw + q * 4 + r;
                    float v = acc[r] * INV_F + sks[(size_t)gn * 64 + col];
                    d_hs[(size_t)gn * 64 + col] = v;
                    p[r] += v * wr;
                }
            } else {
                int i = w - 1;
#pragma unroll
                for (int r = 0; r < 4; r++) {
                    int gn = nw + q * 4 + r;
                    float v = acc[r] * INV_F + skv[(size_t)gn * 192 + i * 64 + col];
                    d_hv[(size_t)gn * 192 + col * 3 + i] = v;
                }
            }
        }
        if (w == 0) {
#pragma unroll
            for (int r = 0; r < 4; r++) {
#pragma unroll
                for (int off = 1; off < 16; off <<= 1) p[r] += __shfl_xor(p[r], off, 64);
                if (l15 == 0) out[nw + q * 4 + r] = p[r] * INV_F;
            }
        }
    }
}

extern "C" void kernel_launch(void* const* d_in, const int* in_sizes, int n_in,
                              void* d_out, int out_size, void* d_ws, size_t ws_size,
                              hipStream_t stream) {
    const float* vectors   = (const float*)d_in[0];
    const float* node_s    = (const float*)d_in[1];
    const float* node_v    = (const float*)d_in[2];
    const float* radial    = (const float*)d_in[3];
    const int*   senders   = (const int*)d_in[4];
    const int*   receivers = (const int*)d_in[5];
    const int*   counts    = (const int*)d_in[6];
    const float* Wup0 = (const float*)d_in[7];
    const float* Wup1 = (const float*)d_in[8];
    const float* R1   = (const float*)d_in[9];
    const float* R2   = (const float*)d_in[10];
    const float* R3   = (const float*)d_in[11];
    const float* R4   = (const float*)d_in[12];
    const float* Wd0  = (const float*)d_in[13];
    const float* Wd1  = (const float*)d_in[14];
    const float* Ws0  = (const float*)d_in[15];
    const float* Ws1  = (const float*)d_in[16];
    const float* Wsc  = (const float*)d_in[17];
    const float* Proj = (const float*)d_in[18];
    const float* Wl0  = (const float*)d_in[19];
    const float* Wl1  = (const float*)d_in[20];
    const float* Wr   = (const float*)d_in[21];
    float* ws  = (float*)d_ws;
    float* out = (float*)d_out;
    unsigned short* frags = (unsigned short*)(ws + OFF_FRAGS);
    unsigned short* wbuf  = (unsigned short*)(ws + OFF_WBUF);
    float4* erec = (float4*)(ws + OFF_CSR);
    int* csr = (int*)(ws + OFF_CSR + (size_t)E_EDGES * 4);
    unsigned short* wf = (unsigned short*)(ws + OFF_WF);

    hipMemsetAsync(csr + CSR_CNT, 0, N_NODES * sizeof(int), stream);
    k_setup<<<(SU_HIST + 255) / 256, 256, 0, stream>>>(
        Wsc, Proj, ws + OFF_WSCP, R1, R2, R3, R4, frags,
        Wup0, Wup1, Ws0, Ws1, Wd0, Wd1, Wl0, Wl1, wf, receivers, csr);
    k_scan_all<<<1, 1024, 0, stream>>>(csr);
    k_pre_bucket<<<2500, 256, 0, stream>>>(node_s, node_v, counts, wf,
                                           vectors, senders, receivers, csr, erec, ws);
    k_mlp<<<5000, 256, 0, stream>>>(radial, frags, csr, erec, wbuf, ws);
    k_tp_gather<<<N_NODES / 4, 256, 0, stream>>>(wbuf, csr, ws);
    k_node_post<<<N_NODES / 16, 256, 0, stream>>>(counts, wf, Wr, ws, out);
}

// Round 15
// 298.357 us; speedup vs baseline: 1.0329x; 1.0329x over previous
//
#include <hip/hip_runtime.h>
#include <hip/hip_bf16.h>
#include <hip/hip_fp16.h>
#include <math.h>

#define N_NODES 20000
#define FCH 64
#define ZSP 10
#define E_EDGES 320000
#define RDIM 8
#define EPSC 0.25f
#define SQRT3C 1.7320508075688772f
#define INV_SQRT3C 0.57735026918962576f
#define INV_F 0.125f  /* 1/sqrt(64) */

// ---- workspace layout (float offsets) ----
#define OFF_EUP    0                               // (N,64) uint2 fp16x4 = N*128 floats
#define OFF_SKS    (N_NODES*128)                   // (N,64)
#define OFF_SKV    (OFF_SKS + N_NODES*64)          // (N,3,64) planar
#define OFF_HSMID  (OFF_SKV + N_NODES*192)         // (N,64)
#define OFF_HVMID  (OFF_HSMID + N_NODES*64)        // (N,3,64) planar
#define OFF_WSCP   (OFF_HVMID + N_NODES*192)       // (Z,9,64)
#define OFF_FRAGS  (OFF_WSCP + ZSP*576)            // 3328*8 ushort = 13312 floats
#define OFF_WBUF   (OFF_FRAGS + 13312)             // E*64 uint2 (fp16x4 MESSAGES)
#define OFF_CSR    (OFF_WBUF + E_EDGES*128)        // erec float4[E], then ints
#define OFF_WF     (OFF_CSR + E_EDGES*4 + 360132)  // 416 slots * 512 ushort
// ints relative to csr int base (after erec):
#define CSR_CNT    0        /* 20000, becomes cursor after scan */
#define CSR_PTR    20000    /* 20001 */
#define CSR_SEID   40001    /* E */

// k_setup gid ranges
#define SU_WSC   5760                  /* 10*576 */
#define SU_PREP  (SU_WSC + 3328)
#define SU_PREP2 (SU_PREP + 26624)     /* 416*64 */
#define SU_HIST  (SU_PREP2 + E_EDGES)

typedef __attribute__((ext_vector_type(8))) short bhalf8;
typedef __attribute__((ext_vector_type(4))) float f32x4;

// fast silu: v_exp_f32 + v_rcp_f32 (err ~1ulp, negligible vs bf16 quantization)
__device__ __forceinline__ float silu_f(float x) {
    float e = __builtin_amdgcn_exp2f(x * -1.442695040888963f);
    return x * __builtin_amdgcn_rcpf(1.0f + e);
}

__device__ __forceinline__ unsigned short f2bf(float x) {
    unsigned int u = __float_as_uint(x);
    unsigned int r = u + 0x7FFFu + ((u >> 16) & 1u);   // RNE
    return (unsigned short)(r >> 16);
}

// packed pair -> one dword (lo in low 16); v_cvt_pk_bf16_f32 on gfx950
__device__ __forceinline__ unsigned int pack_bf2(float lo, float hi) {
    __hip_bfloat162 b = __float22bfloat162_rn(make_float2(lo, hi));
    return *(unsigned int*)&b;
}

// fp16 pair pack (lo in low 16)
__device__ __forceinline__ unsigned int pack_h2(float lo, float hi) {
    __half2 h = __floats2half2_rn(lo, hi);
    return *(unsigned int*)&h;
}

__device__ __forceinline__ bhalf8 mk8(unsigned a, unsigned b, unsigned c, unsigned d) {
    uint4 u; u.x = a; u.y = b; u.z = c; u.w = d;
    return *(bhalf8*)&u;
}

__device__ __forceinline__ float half_lo(unsigned v) {
    return __half2float(__ushort_as_half((unsigned short)(v & 0xFFFFu)));
}
__device__ __forceinline__ float half_hi(unsigned v) {
    return __half2float(__ushort_as_half((unsigned short)(v >> 16)));
}

// split fp32 -> bf16 hi (trunc) + bf16 lo (trunc of residual); err ~2^-16 rel
__device__ __forceinline__ void split_f32(float x, short& h, short& l) {
    unsigned int u = __float_as_uint(x);
    unsigned int hb = u & 0xFFFF0000u;
    h = (short)(u >> 16);
    float r = x - __uint_as_float(hb);
    l = (short)(__float_as_uint(r) >> 16);
}

__device__ __forceinline__ int species_of(int n, const int* counts) {
    int acc = 0, s = ZSP - 1;
#pragma unroll
    for (int z = 0; z < ZSP; z++) {
        int c = counts[z];
        if (n >= acc && n < acc + c) s = z;
        acc += c;
    }
    return s;
}

// K-setup: fused wscproj + prep(MLP frags) + prep2(node frags) + hist.
__global__ __launch_bounds__(256) void k_setup(
    const float* __restrict__ Wsc, const float* __restrict__ Proj, float* __restrict__ wscp,
    const float* __restrict__ R1, const float* __restrict__ R2,
    const float* __restrict__ R3, const float* __restrict__ R4,
    unsigned short* __restrict__ frags,
    const float* __restrict__ Wup0, const float* __restrict__ Wup1,
    const float* __restrict__ Ws0, const float* __restrict__ Ws1,
    const float* __restrict__ Wd0, const float* __restrict__ Wd1,
    const float* __restrict__ Wl0, const float* __restrict__ Wl1,
    unsigned short* __restrict__ wf,
    const int* __restrict__ receivers, int* __restrict__ csr) {
    int gid = blockIdx.x * 256 + threadIdx.x;
    if (gid < SU_WSC) {
        int z = gid / 576, t = gid % 576;
        int b = t >> 6, u = t & 63;
        float acc = 0.f;
#pragma unroll
        for (int p = 0; p < 9; p++) acc += Wsc[z * 576 + p * 64 + u] * Proj[p * 9 + b];
        wscp[z * 576 + b * 64 + u] = acc;
    } else if (gid < SU_PREP) {
        int id = gid - SU_WSC;
        int lane = id & 63, fi = id >> 6;
        int quad = lane >> 4, l15 = lane & 15;
        const float* W;
        int s, t, N;
        bool r1 = false;
        if (fi < 4)       { W = R1; s = 0; t = fi; N = 64; r1 = true; }
        else if (fi < 12) { W = R2; int x = fi - 4;  s = x >> 2; t = x & 3;  N = 64; }
        else if (fi < 20) { W = R3; int x = fi - 12; s = x >> 2; t = x & 3;  N = 64; }
        else              { W = R4; int x = fi - 20; s = x >> 4; t = x & 15; N = 256; }
        unsigned int v[4];
#pragma unroll
        for (int jj = 0; jj < 4; jj++) {
            unsigned short pk2[2];
#pragma unroll
            for (int o = 0; o < 2; o++) {
                int j = jj * 2 + o;
                int k = s * 32 + quad * 8 + j, n = t * 16 + l15;
                float val = (r1 && k >= RDIM) ? 0.f : W[k * N + n];
                pk2[o] = f2bf(val);
            }
            v[jj] = (unsigned int)pk2[0] | ((unsigned int)pk2[1] << 16);
        }
        uint4 pk; pk.x = v[0]; pk.y = v[1]; pk.z = v[2]; pk.w = v[3];
        ((uint4*)frags)[id] = pk;
    } else if (gid < SU_PREP2) {
        int id = gid - SU_PREP;
        int lane = id & 63, slot = id >> 6;
        int t = slot & 3, s = (slot >> 2) & 1, part = (slot >> 3) & 1, mat = slot >> 4;
        int quad = lane >> 4, l15 = lane & 15;
        const float* W;
        if (mat == 0)       W = Wup0;
        else if (mat == 1)  W = Wup1;
        else if (mat < 12)  W = Ws0 + (mat - 2) * 4096;
        else if (mat < 22)  W = Ws1 + (mat - 12) * 4096;
        else if (mat == 22) W = Wd0;
        else if (mat == 23) W = Wd1;
        else if (mat == 24) W = Wl0;
        else                W = Wl1;
        unsigned int v[4];
#pragma unroll
        for (int jj = 0; jj < 4; jj++) {
            unsigned short pk2[2];
#pragma unroll
            for (int o = 0; o < 2; o++) {
                int j = jj * 2 + o;
                int k = s * 32 + quad * 8 + j, n = t * 16 + l15;
                float x = W[k * 64 + n];
                short h, l;
                split_f32(x, h, l);
                pk2[o] = part == 0 ? (unsigned short)h : (unsigned short)l;
            }
            v[jj] = (unsigned int)pk2[0] | ((unsigned int)pk2[1] << 16);
        }
        uint4 pk; pk.x = v[0]; pk.y = v[1]; pk.z = v[2]; pk.w = v[3];
        ((uint4*)wf)[id] = pk;
    } else if (gid < SU_HIST) {
        int e = gid - SU_PREP2;
        atomicAdd(&csr[CSR_CNT + receivers[e]], 1);
    }
}

// Single-dispatch scan: one block, 1024 threads, shuffle-based.
__global__ __launch_bounds__(1024) void k_scan_all(int* __restrict__ csr) {
    __shared__ int wsum[16];
    __shared__ int carry;
    int t = threadIdx.x, lane = t & 63, wv = t >> 6;
    int running = 0;
    for (int i0 = 0; i0 < N_NODES; i0 += 1024) {
        int i = i0 + t;
        int x = (i < N_NODES) ? csr[CSR_CNT + i] : 0;
        int s = x;
#pragma unroll
        for (int off = 1; off < 64; off <<= 1) {
            int v = __shfl_up(s, off, 64);
            if (lane >= off) s += v;
        }
        if (lane == 63) wsum[wv] = s;
        __syncthreads();
        if (wv == 0 && lane < 16) {
            int v = wsum[lane];
            int sc = v;
#pragma unroll
            for (int off = 1; off < 16; off <<= 1) {
                int u = __shfl_up(sc, off, 64);
                if (lane >= off) sc += u;
            }
            wsum[lane] = sc - v;       // exclusive wave offset
            if (lane == 15) carry = sc; // iteration total
        }
        __syncthreads();
        int excl = s - x + wsum[wv];
        if (i < N_NODES) {
            int val = running + excl;
            csr[CSR_PTR + i] = val;
            csr[CSR_CNT + i] = val;     // cursor for bucketing
        }
        running += carry;
        __syncthreads();               // protect wsum/carry before next iter
    }
    if (t == 0) csr[CSR_PTR + N_NODES] = running;
}

// Merged: blocks 0..1249 = node_pre (linear_up fp16-packed + species skip),
//         blocks 1250..2499 = bucket (CSR fill + Y1/sender precompute).
__global__ __launch_bounds__(256) void k_pre_bucket(
    const float* __restrict__ ns, const float* __restrict__ nv,
    const int* __restrict__ counts, const unsigned short* __restrict__ wf,
    const float* __restrict__ vectors, const int* __restrict__ senders,
    const int* __restrict__ receivers, int* __restrict__ csr,
    float4* __restrict__ erec, float* __restrict__ ws) {
    __shared__ uint2 eup_t[16][64];   // 8 KB (node_pre blocks only)
    int tid = threadIdx.x;
    if (blockIdx.x >= 1250) {
        // ---- bucket ----
        int e = (blockIdx.x - 1250) * 256 + tid;   // 1250*256 == E exactly
        int pos = atomicAdd(&csr[CSR_CNT + receivers[e]], 1);
        float v0 = vectors[e * 3 + 0], v1 = vectors[e * 3 + 1], v2 = vectors[e * 3 + 2];
        float s = SQRT3C * rsqrtf(v0 * v0 + v1 * v1 + v2 * v2);
        csr[CSR_SEID + pos] = e;
        float4 r;
        r.x = v0 * s; r.y = v1 * s; r.z = v2 * s; r.w = __int_as_float(senders[e]);
        erec[pos] = r;
        return;
    }
    // ---- node_pre ----
    int w = tid >> 6, lane = tid & 63;
    int q = lane >> 4, l15 = lane & 15;
    int nw = blockIdx.x * 16;
    int sid = species_of(nw, counts);
    const f32x4 z4 = {0.f, 0.f, 0.f, 0.f};

    bhalf8 Ah[2], Al[2];
    if (w == 0) {
#pragma unroll
        for (int s = 0; s < 2; s++) {
            const float* rp = ns + (size_t)(nw + l15) * 64 + s * 32 + q * 8;
            float4 a = *(const float4*)rp, b = *(const float4*)(rp + 4);
            float x[8] = {a.x, a.y, a.z, a.w, b.x, b.y, b.z, b.w};
#pragma unroll
            for (int j = 0; j < 8; j++) { short h, l; split_f32(x[j], h, l); Ah[s][j] = h; Al[s][j] = l; }
        }
    } else {
        int i = w - 1;
#pragma unroll
        for (int s = 0; s < 2; s++) {
            const float* rp = nv + (size_t)(nw + l15) * 192 + i;
#pragma unroll
            for (int j = 0; j < 8; j++) {
                float x = rp[(s * 32 + q * 8 + j) * 3];
                short h, l; split_f32(x, h, l); Ah[s][j] = h; Al[s][j] = l;
            }
        }
    }

    const bhalf8* wfv = (const bhalf8*)wf;
    float* sks = ws + OFF_SKS;
    float* skv = ws + OFF_SKV;

    // m=0: linear_up -> fp16 packed LDS tile
    {
        int mat = (w == 0) ? 0 : 1;
#pragma unroll
        for (int t = 0; t < 4; t++) {
            f32x4 acc = z4;
#pragma unroll
            for (int s = 0; s < 2; s++) {
                bhalf8 bh = wfv[(size_t)(mat * 16 + 0 + s * 4 + t) * 64 + lane];
                bhalf8 bl = wfv[(size_t)(mat * 16 + 8 + s * 4 + t) * 64 + lane];
                acc = __builtin_amdgcn_mfma_f32_16x16x32_bf16(Ah[s], bh, acc, 0, 0, 0);
                acc = __builtin_amdgcn_mfma_f32_16x16x32_bf16(Al[s], bh, acc, 0, 0, 0);
                acc = __builtin_amdgcn_mfma_f32_16x16x32_bf16(Ah[s], bl, acc, 0, 0, 0);
            }
#pragma unroll
            for (int r = 0; r < 4; r++) {
                unsigned short us = __half_as_ushort(__float2half_rn(acc[r] * INV_F));
                ((unsigned short*)&eup_t[q * 4 + r][t * 16 + l15])[w] = us;
            }
        }
    }
    // m=1: species skip -> fp32 tables
    {
        int mat = (w == 0) ? 2 + sid : 12 + sid;
        float* dst = (w == 0) ? sks : skv;
        int stride = (w == 0) ? 64 : 192;
        int off = (w == 0) ? 0 : (w - 1) * 64;
#pragma unroll
        for (int t = 0; t < 4; t++) {
            f32x4 acc = z4;
#pragma unroll
            for (int s = 0; s < 2; s++) {
                bhalf8 bh = wfv[(size_t)(mat * 16 + 0 + s * 4 + t) * 64 + lane];
                bhalf8 bl = wfv[(size_t)(mat * 16 + 8 + s * 4 + t) * 64 + lane];
                acc = __builtin_amdgcn_mfma_f32_16x16x32_bf16(Ah[s], bh, acc, 0, 0, 0);
                acc = __builtin_amdgcn_mfma_f32_16x16x32_bf16(Al[s], bh, acc, 0, 0, 0);
                acc = __builtin_amdgcn_mfma_f32_16x16x32_bf16(Ah[s], bl, acc, 0, 0, 0);
            }
#pragma unroll
            for (int r = 0; r < 4; r++)
                dst[(size_t)(nw + q * 4 + r) * stride + off + t * 16 + l15] = acc[r] * INV_F;
        }
    }
    __syncthreads();
    uint2* eup = (uint2*)(ws + OFF_EUP);
    for (int k = tid; k < 1024; k += 256) {
        int n = k >> 6, f = k & 63;
        eup[(size_t)(nw + n) * 64 + f] = eup_t[n][f];
    }
}

// Cross-lane frag builder (see R9 derivation).
template<int S>
__device__ __forceinline__ bhalf8 xfrag(const unsigned* pkA, const unsigned* pkB,
                                        int q, int l15) {
    int L0 = ((q & 1) << 5) + l15;
    int L1 = L0 + 16;
    bool hi = (q >> 1) != 0;
    unsigned a0 = (unsigned)__shfl((int)pkA[2 * S], L0, 64);
    unsigned a1 = (unsigned)__shfl((int)pkA[2 * S + 1], L0, 64);
    unsigned b0 = (unsigned)__shfl((int)pkB[2 * S], L0, 64);
    unsigned b1 = (unsigned)__shfl((int)pkB[2 * S + 1], L0, 64);
    unsigned c0 = (unsigned)__shfl((int)pkA[2 * S], L1, 64);
    unsigned c1 = (unsigned)__shfl((int)pkA[2 * S + 1], L1, 64);
    unsigned e0 = (unsigned)__shfl((int)pkB[2 * S], L1, 64);
    unsigned e1 = (unsigned)__shfl((int)pkB[2 * S + 1], L1, 64);
    return mk8(hi ? a1 : a0, hi ? b1 : b0, hi ? c1 : c0, hi ? e1 : e0);
}

// K2a: radial MLP via bf16 MFMA + full message computation (R13 structure:
// r4lds staging RESTORED). Change vs R13: the 16 eup gathers + erec loads are
// hoisted to right after layer 1 (where r1f dies), giving them layers 2-3
// (~hundreds of cycles) to land instead of 8 MFMAs.
__global__ __launch_bounds__(256) void k_mlp(
    const float* __restrict__ radial, const unsigned short* __restrict__ frags,
    const int* __restrict__ csr, const float4* __restrict__ erec,
    unsigned short* __restrict__ wbuf, const float* __restrict__ ws) {
    __shared__ unsigned short r4lds[16384];   // 32 KB
    int tid = threadIdx.x;
    int lane = tid & 63, w = tid >> 6, quad = lane >> 4, l15 = lane & 15;

    const uint4* r4g = (const uint4*)(frags + 20 * 64 * 8);
    uint4* r4l = (uint4*)r4lds;
    for (int i = tid; i < 2048; i += 256) r4l[i] = r4g[i];
    const bhalf8* fr = (const bhalf8*)frags;
    bhalf8 r1f[4], r2f[2][4], r3f[2][4];
#pragma unroll
    for (int t = 0; t < 4; t++) r1f[t] = fr[t * 64 + lane];
#pragma unroll
    for (int s = 0; s < 2; s++)
#pragma unroll
        for (int t = 0; t < 4; t++) {
            r2f[s][t] = fr[(4 + s * 4 + t) * 64 + lane];
            r3f[s][t] = fr[(12 + s * 4 + t) * 64 + lane];
        }
    __syncthreads();

    const f32x4 z4 = {0.f, 0.f, 0.f, 0.f};
    const bhalf8* r4f = (const bhalf8*)r4lds;
    const uint2* eup = (const uint2*)(ws + OFF_EUP);

    int el0 = (blockIdx.x * 4 + w) * 16;   // global sorted slot base

    bhalf8 af = {0, 0, 0, 0, 0, 0, 0, 0};
    if (quad == 0) {
        int eid = csr[CSR_SEID + el0 + l15];  // global edge id
        const float* rp = radial + (size_t)eid * 8;
        float4 ra = *(const float4*)rp;
        float4 rb = *(const float4*)(rp + 4);
        af[0] = (short)f2bf(ra.x); af[1] = (short)f2bf(ra.y);
        af[2] = (short)f2bf(ra.z); af[3] = (short)f2bf(ra.w);
        af[4] = (short)f2bf(rb.x); af[5] = (short)f2bf(rb.y);
        af[6] = (short)f2bf(rb.z); af[7] = (short)f2bf(rb.w);
    }
    unsigned pkA[4], pkB[4];
    {
        f32x4 acc[4];
#pragma unroll
        for (int t = 0; t < 4; t++)
            acc[t] = __builtin_amdgcn_mfma_f32_16x16x32_bf16(r1f[t], af, z4, 0, 0, 0);
#pragma unroll
        for (int t = 0; t < 4; t++) {
            pkA[t] = pack_bf2(silu_f(acc[t][0]), silu_f(acc[t][1]));
            pkB[t] = pack_bf2(silu_f(acc[t][2]), silu_f(acc[t][3]));
        }
    }
    // ---- hoisted TP-epilogue loads: erec (broadcast) + 16 eup gathers ----
    float4 rc[4];
    int sx[4];
#pragma unroll
    for (int r = 0; r < 4; r++) {
        rc[r] = erec[el0 + quad * 4 + r];
        sx[r] = __float_as_int(rc[r].w);
    }
    uint2 ev[4][4];   // [t4][r]
#pragma unroll
    for (int t4 = 0; t4 < 4; t4++)
#pragma unroll
        for (int r = 0; r < 4; r++)
            ev[t4][r] = eup[(size_t)sx[r] * 64 + t4 * 16 + l15];
    // ---- layers 2, 3 (gathers in flight underneath) ----
#pragma unroll
    for (int layer = 0; layer < 2; layer++) {
        bhalf8 b0 = xfrag<0>(pkA, pkB, quad, l15);
        bhalf8 b1 = xfrag<1>(pkA, pkB, quad, l15);
        f32x4 acc[4];
#pragma unroll
        for (int t = 0; t < 4; t++) {
            bhalf8 w0 = layer == 0 ? r2f[0][t] : r3f[0][t];
            bhalf8 w1 = layer == 0 ? r2f[1][t] : r3f[1][t];
            acc[t] = __builtin_amdgcn_mfma_f32_16x16x32_bf16(
                w1, b1, __builtin_amdgcn_mfma_f32_16x16x32_bf16(w0, b0, z4, 0, 0, 0), 0, 0, 0);
        }
#pragma unroll
        for (int t = 0; t < 4; t++) {
            pkA[t] = pack_bf2(silu_f(acc[t][0]), silu_f(acc[t][1]));
            pkB[t] = pack_bf2(silu_f(acc[t][2]), silu_f(acc[t][3]));
        }
    }
    // ---- layer 4 + TP epilogue ----
    {
        bhalf8 a0 = xfrag<0>(pkA, pkB, quad, l15);
        bhalf8 a1 = xfrag<1>(pkA, pkB, quad, l15);
#pragma unroll
        for (int t4 = 0; t4 < 4; t4++) {
            int f = t4 * 16 + l15;
            f32x4 p0 = __builtin_amdgcn_mfma_f32_16x16x32_bf16(
                a1, r4f[(16 + t4) * 64 + lane],
                __builtin_amdgcn_mfma_f32_16x16x32_bf16(a0, r4f[t4 * 64 + lane], z4, 0, 0, 0), 0, 0, 0);
            f32x4 p1 = __builtin_amdgcn_mfma_f32_16x16x32_bf16(
                a1, r4f[(20 + t4) * 64 + lane],
                __builtin_amdgcn_mfma_f32_16x16x32_bf16(a0, r4f[(4 + t4) * 64 + lane], z4, 0, 0, 0), 0, 0, 0);
            f32x4 p2 = __builtin_amdgcn_mfma_f32_16x16x32_bf16(
                a1, r4f[(24 + t4) * 64 + lane],
                __builtin_amdgcn_mfma_f32_16x16x32_bf16(a0, r4f[(8 + t4) * 64 + lane], z4, 0, 0, 0), 0, 0, 0);
            f32x4 p3 = __builtin_amdgcn_mfma_f32_16x16x32_bf16(
                a1, r4f[(28 + t4) * 64 + lane],
                __builtin_amdgcn_mfma_f32_16x16x32_bf16(a0, r4f[(12 + t4) * 64 + lane], z4, 0, 0, 0), 0, 0, 0);
#pragma unroll
            for (int r = 0; r < 4; r++) {
                float es = half_lo(ev[t4][r].x), e0 = half_hi(ev[t4][r].x);
                float e1 = half_lo(ev[t4][r].y), e2 = half_hi(ev[t4][r].y);
                float dot = e0 * rc[r].x + e1 * rc[r].y + e2 * rc[r].z;
                float ms = p0[r] * es + p1[r] * dot * INV_SQRT3C;
                float t3 = p3[r] * es * INV_SQRT3C;
                float m0 = p2[r] * e0 + t3 * rc[r].x;
                float m1 = p2[r] * e1 + t3 * rc[r].y;
                float m2 = p2[r] * e2 + t3 * rc[r].z;
                int el = el0 + quad * 4 + r;
                uint2 pk;
                pk.x = pack_h2(ms, m0);
                pk.y = pack_h2(m1, m2);
                ((uint2*)wbuf)[(size_t)el * 64 + f] = pk;
            }
        }
    }
}

// K2b: pure-stream message reduction per node. No random reads at all.
__global__ __launch_bounds__(256) void k_tp_gather(
    const unsigned short* __restrict__ wbuf, const int* __restrict__ csr,
    float* __restrict__ ws) {
    int tid = threadIdx.x, w = tid >> 6, f = tid & 63;
    int n = blockIdx.x * 4 + w;
    float* hs_mid = ws + OFF_HSMID;
    float* hv_mid = ws + OFF_HVMID;
    int beg = csr[CSR_PTR + n], end = csr[CSR_PTR + n + 1];
    float ams = 0.f, am0 = 0.f, am1 = 0.f, am2 = 0.f;
    if (beg < end) {
        int last = end - 1;
        uint2 mA = ((const uint2*)wbuf)[(size_t)beg * 64 + f];
        for (int i = beg; i < end; i++) {
            int j1 = (i + 1 < end) ? i + 1 : last;
            uint2 mB = ((const uint2*)wbuf)[(size_t)j1 * 64 + f];
            ams += half_lo(mA.x); am0 += half_hi(mA.x);
            am1 += half_lo(mA.y); am2 += half_hi(mA.y);
            mA = mB;
        }
    }
    hs_mid[n * 64 + f] = ams * EPSC;
    hv_mid[n * 192 + f] = am0 * EPSC;
    hv_mid[n * 192 + 64 + f] = am1 * EPSC;
    hv_mid[n * 192 + 128 + f] = am2 * EPSC;
}

// K3: linear_down + contraction + linear_sc + skip + readout via split-bf16 MFMA.
__global__ __launch_bounds__(256) void k_node_post(
    const int* __restrict__ counts, const unsigned short* __restrict__ wf,
    const float* __restrict__ Wr, float* __restrict__ ws, float* __restrict__ out) {
    __shared__ float T[4][16][68];
    int tid = threadIdx.x, w = tid >> 6, lane = tid & 63;
    int q = lane >> 4, l15 = lane & 15;
    int nw = blockIdx.x * 16;
    int sid = species_of(nw, counts);
    const f32x4 z4 = {0.f, 0.f, 0.f, 0.f};
    const bhalf8* wfv = (const bhalf8*)wf;
    const float* hs_mid = ws + OFF_HSMID;
    const float* hv_mid = ws + OFF_HVMID;
    const float* sks = ws + OFF_SKS;
    const float* skv = ws + OFF_SKV;
    const float* wscp = ws + OFF_WSCP;

    // Phase 1: linear_down (EPS already applied in k_tp_gather's store)
    {
        const float* src = (w == 0) ? hs_mid + (size_t)nw * 64
                                    : hv_mid + (size_t)nw * 192 + (w - 1) * 64;
        int rstride = (w == 0) ? 64 : 192;
        bhalf8 Ah[2], Al[2];
#pragma unroll
        for (int s = 0; s < 2; s++) {
            const float* rp = src + (size_t)l15 * rstride + s * 32 + q * 8;
            float4 a = *(const float4*)rp, b = *(const float4*)(rp + 4);
            float x[8] = {a.x, a.y, a.z, a.w, b.x, b.y, b.z, b.w};
#pragma unroll
            for (int j = 0; j < 8; j++) { short h, l; split_f32(x[j], h, l); Ah[s][j] = h; Al[s][j] = l; }
        }
        int mat = (w == 0) ? 22 : 23;
#pragma unroll
        for (int t = 0; t < 4; t++) {
            f32x4 acc = z4;
#pragma unroll
            for (int s = 0; s < 2; s++) {
                bhalf8 bh = wfv[(size_t)(mat * 16 + 0 + s * 4 + t) * 64 + lane];
                bhalf8 bl = wfv[(size_t)(mat * 16 + 8 + s * 4 + t) * 64 + lane];
                acc = __builtin_amdgcn_mfma_f32_16x16x32_bf16(Ah[s], bh, acc, 0, 0, 0);
                acc = __builtin_amdgcn_mfma_f32_16x16x32_bf16(Al[s], bh, acc, 0, 0, 0);
                acc = __builtin_amdgcn_mfma_f32_16x16x32_bf16(Ah[s], bl, acc, 0, 0, 0);
            }
#pragma unroll
            for (int r = 0; r < 4; r++)
                T[w][q * 4 + r][t * 16 + l15] = acc[r] * INV_F;
        }
    }
    __syncthreads();

    // Phase 2: symmetric contraction
    {
        int col = tid & 63, rg = tid >> 6;
        float wv[9];
#pragma unroll
        for (int b = 0; b < 9; b++) wv[b] = wscp[sid * 576 + b * 64 + col];
#pragma unroll
        for (int rr = 0; rr < 4; rr++) {
            int row = rg * 4 + rr;
            float hs = T[0][row][col];
            float h0 = T[1][row][col], h1 = T[2][row][col], h2 = T[3][row][col];
            float vv = h0 * h0 + h1 * h1 + h2 * h2;
            float cs = wv[0] * hs + wv[1] * hs * hs + wv[2] * vv
                     + wv[3] * hs * hs * hs + wv[4] * hs * vv;
            float fv = wv[5] + wv[6] * hs + wv[7] * hs * hs + wv[8] * vv;
            T[0][row][col] = cs;
            T[1][row][col] = h0 * fv;
            T[2][row][col] = h1 * fv;
            T[3][row][col] = h2 * fv;
        }
    }
    __syncthreads();

    // Phase 3: linear_sc + skip + store (+ readout on w0)
    {
        bhalf8 Ah[2], Al[2];
#pragma unroll
        for (int s = 0; s < 2; s++) {
            const float* rp = &T[w][l15][s * 32 + q * 8];
            float4 a = *(const float4*)rp, b = *(const float4*)(rp + 4);
            float x[8] = {a.x, a.y, a.z, a.w, b.x, b.y, b.z, b.w};
#pragma unroll
            for (int j = 0; j < 8; j++) { short h, l; split_f32(x[j], h, l); Ah[s][j] = h; Al[s][j] = l; }
        }
        int mat = (w == 0) ? 24 : 25;
        float* d_hs = out + N_NODES;
        float* d_hv = out + N_NODES + N_NODES * 64;
        float p[4] = {0.f, 0.f, 0.f, 0.f};
#pragma unroll
        for (int t = 0; t < 4; t++) {
            f32x4 acc = z4;
#pragma unroll
            for (int s = 0; s < 2; s++) {
                bhalf8 bh = wfv[(size_t)(mat * 16 + 0 + s * 4 + t) * 64 + lane];
                bhalf8 bl = wfv[(size_t)(mat * 16 + 8 + s * 4 + t) * 64 + lane];
                acc = __builtin_amdgcn_mfma_f32_16x16x32_bf16(Ah[s], bh, acc, 0, 0, 0);
                acc = __builtin_amdgcn_mfma_f32_16x16x32_bf16(Al[s], bh, acc, 0, 0, 0);
                acc = __builtin_amdgcn_mfma_f32_16x16x32_bf16(Ah[s], bl, acc, 0, 0, 0);
            }
            int col = t * 16 + l15;
            if (w == 0) {
                float wr = Wr[col];
#pragma unroll
                for (int r = 0; r < 4; r++) {
                    int gn = nw + q * 4 + r;
                    float v = acc[r] * INV_F + sks[(size_t)gn * 64 + col];
                    d_hs[(size_t)gn * 64 + col] = v;
                    p[r] += v * wr;
                }
            } else {
                int i = w - 1;
#pragma unroll
                for (int r = 0; r < 4; r++) {
                    int gn = nw + q * 4 + r;
                    float v = acc[r] * INV_F + skv[(size_t)gn * 192 + i * 64 + col];
                    d_hv[(size_t)gn * 192 + col * 3 + i] = v;
                }
            }
        }
        if (w == 0) {
#pragma unroll
            for (int r = 0; r < 4; r++) {
#pragma unroll
                for (int off = 1; off < 16; off <<= 1) p[r] += __shfl_xor(p[r], off, 64);
                if (l15 == 0) out[nw + q * 4 + r] = p[r] * INV_F;
            }
        }
    }
}

extern "C" void kernel_launch(void* const* d_in, const int* in_sizes, int n_in,
                              void* d_out, int out_size, void* d_ws, size_t ws_size,
                              hipStream_t stream) {
    const float* vectors   = (const float*)d_in[0];
    const float* node_s    = (const float*)d_in[1];
    const float* node_v    = (const float*)d_in[2];
    const float* radial    = (const float*)d_in[3];
    const int*   senders   = (const int*)d_in[4];
    const int*   receivers = (const int*)d_in[5];
    const int*   counts    = (const int*)d_in[6];
    const float* Wup0 = (const float*)d_in[7];
    const float* Wup1 = (const float*)d_in[8];
    const float* R1   = (const float*)d_in[9];
    const float* R2   = (const float*)d_in[10];
    const float* R3   = (const float*)d_in[11];
    const float* R4   = (const float*)d_in[12];
    const float* Wd0  = (const float*)d_in[13];
    const float* Wd1  = (const float*)d_in[14];
    const float* Ws0  = (const float*)d_in[15];
    const float* Ws1  = (const float*)d_in[16];
    const float* Wsc  = (const float*)d_in[17];
    const float* Proj = (const float*)d_in[18];
    const float* Wl0  = (const float*)d_in[19];
    const float* Wl1  = (const float*)d_in[20];
    const float* Wr   = (const float*)d_in[21];
    float* ws  = (float*)d_ws;
    float* out = (float*)d_out;
    unsigned short* frags = (unsigned short*)(ws + OFF_FRAGS);
    unsigned short* wbuf  = (unsigned short*)(ws + OFF_WBUF);
    float4* erec = (float4*)(ws + OFF_CSR);
    int* csr = (int*)(ws + OFF_CSR + (size_t)E_EDGES * 4);
    unsigned short* wf = (unsigned short*)(ws + OFF_WF);

    hipMemsetAsync(csr + CSR_CNT, 0, N_NODES * sizeof(int), stream);
    k_setup<<<(SU_HIST + 255) / 256, 256, 0, stream>>>(
        Wsc, Proj, ws + OFF_WSCP, R1, R2, R3, R4, frags,
        Wup0, Wup1, Ws0, Ws1, Wd0, Wd1, Wl0, Wl1, wf, receivers, csr);
    k_scan_all<<<1, 1024, 0, stream>>>(csr);
    k_pre_bucket<<<2500, 256, 0, stream>>>(node_s, node_v, counts, wf,
                                           vectors, senders, receivers, csr, erec, ws);
    k_mlp<<<5000, 256, 0, stream>>>(radial, frags, csr, erec, wbuf, ws);
    k_tp_gather<<<N_NODES / 4, 256, 0, stream>>>(wbuf, csr, ws);
    k_node_post<<<N_NODES / 16, 256, 0, stream>>>(counts, wf, Wr, ws, out);
}